// Round 1
// baseline (47.476 us; speedup 1.0000x reference)
//
#include <hip/hip_runtime.h>
#include <hip/hip_bf16.h>

// Additive attention weights: B=2,H=4,LQ=LKV=512,D=64, fp32 in/out.
// Key identities:
//   tanh(x) = 1 - 2/(1+e^{2x});  logit = sum_e w_e*tanh(.) + b_logit
//   softmax is invariant to the uniform shift (sum_e w_e + b_logit), so
//   effective logit = sum_e (-2 w_e) * 1/(1 + exp2((qp+kp+b)*2*log2e))
// Kernel A precomputes qs=(qp+b_concat)*2log2e, ks=kp*2log2e into d_ws.

#define NQROWS 4096   // B*H*LQ

__device__ __forceinline__ float sig2(float x) {
  // 1 / (1 + exp2(x))
  const float u = __builtin_amdgcn_exp2f(x);
  return __builtin_amdgcn_rcpf(1.0f + u);
}

// ---------------- kernel A: projections ----------------
// 16 rows per block; rows [0,4096) from Q, [4096,8192) from K.
__global__ __launch_bounds__(256) void proj_kernel(
    const float* __restrict__ Q, const float* __restrict__ K,
    const float* __restrict__ W, const float* __restrict__ bC,
    float* __restrict__ qs, float* __restrict__ ks)
{
  const int t  = threadIdx.x;
  const int tr = t >> 6;        // 0..3
  const int e  = t & 63;
  const int rbase = blockIdx.x * 16;
  const bool isK = rbase >= NQROWS;
  const int r0 = isK ? rbase - NQROWS : rbase;
  const float* __restrict__ src = isK ? K : Q;
  const int off = isK ? 64 : 0;

  __shared__ float  srow[16][64];    // 4KB, broadcast reads
  __shared__ float4 wsh[64][16];     // 16KB, XOR-swizzled (f4 col ^ (row&7))

  for (int i = t; i < 16 * 64; i += 256)
    srow[i >> 6][i & 63] = src[(r0 + (i >> 6)) * 64 + (i & 63)];
  for (int i = t; i < 64 * 16; i += 256) {
    const int er = i >> 4, d4 = i & 15;
    wsh[er][d4 ^ (er & 7)] =
        reinterpret_cast<const float4*>(W + er * 128 + off)[d4];
  }
  __syncthreads();

  float acc0 = 0.f, acc1 = 0.f, acc2 = 0.f, acc3 = 0.f;
  const int rA = tr * 4;
  #pragma unroll
  for (int d4 = 0; d4 < 16; ++d4) {
    const float4 w4 = wsh[e][d4 ^ (e & 7)];
    const float4 s0 = *reinterpret_cast<const float4*>(&srow[rA + 0][d4 * 4]);
    const float4 s1 = *reinterpret_cast<const float4*>(&srow[rA + 1][d4 * 4]);
    const float4 s2 = *reinterpret_cast<const float4*>(&srow[rA + 2][d4 * 4]);
    const float4 s3 = *reinterpret_cast<const float4*>(&srow[rA + 3][d4 * 4]);
    acc0 = fmaf(s0.x, w4.x, acc0); acc0 = fmaf(s0.y, w4.y, acc0);
    acc0 = fmaf(s0.z, w4.z, acc0); acc0 = fmaf(s0.w, w4.w, acc0);
    acc1 = fmaf(s1.x, w4.x, acc1); acc1 = fmaf(s1.y, w4.y, acc1);
    acc1 = fmaf(s1.z, w4.z, acc1); acc1 = fmaf(s1.w, w4.w, acc1);
    acc2 = fmaf(s2.x, w4.x, acc2); acc2 = fmaf(s2.y, w4.y, acc2);
    acc2 = fmaf(s2.z, w4.z, acc2); acc2 = fmaf(s2.w, w4.w, acc2);
    acc3 = fmaf(s3.x, w4.x, acc3); acc3 = fmaf(s3.y, w4.y, acc3);
    acc3 = fmaf(s3.z, w4.z, acc3); acc3 = fmaf(s3.w, w4.w, acc3);
  }

  const float C2 = 2.8853900817779268f;   // 2*log2(e)
  const float bias = isK ? 0.0f : bC[e];
  float* __restrict__ dst = isK ? ks : qs;
  dst[(r0 + rA + 0) * 64 + e] = (acc0 + bias) * C2;
  dst[(r0 + rA + 1) * 64 + e] = (acc1 + bias) * C2;
  dst[(r0 + rA + 2) * 64 + e] = (acc2 + bias) * C2;
  dst[(r0 + rA + 3) * 64 + e] = (acc3 + bias) * C2;
}

// ---------------- kernel B: fused logits + masked softmax ----------------
// Grid: 512 blocks (bh 0..7 x qblk 0..63), 256 threads.
// Block = 8 q-rows x full K=512. Thread (tqg=t>>6, tk=t&63):
//   q rows {qblk*8 + tqg*2 + qq}, k = tile*128 + jj*64 + tk.
// Each wave owns exactly 2 rows -> full-wave shfl reductions.
__global__ __launch_bounds__(256) void attn_kernel(
    const float* __restrict__ qs, const float* __restrict__ ks,
    const float* __restrict__ wl, const int* __restrict__ mask,
    float* __restrict__ out)
{
  const int t    = threadIdx.x;
  const int tqg  = t >> 6;
  const int tk   = t & 63;
  const int blk  = blockIdx.x;
  const int bh   = blk >> 6;      // 0..7
  const int qblk = blk & 63;
  const int b    = bh >> 2;       // H=4
  const int q0   = qblk * 8 + tqg * 2;

  __shared__ float  qsh[8][64];       // broadcast reads (wave-uniform)
  __shared__ float  w2s[64];          // -2*w_logit, broadcast reads
  __shared__ float4 kp4[128][16];     // 32KB, XOR-swizzled

  if (t < 64) w2s[t] = -2.0f * wl[t];
  for (int i = t; i < 8 * 64; i += 256)
    qsh[i >> 6][i & 63] = qs[(bh * 512 + qblk * 8 + (i >> 6)) * 64 + (i & 63)];

  const float* __restrict__ kbase = ks + bh * 512 * 64;

  float acc[2][8];
  #pragma unroll
  for (int qq = 0; qq < 2; ++qq)
    #pragma unroll
    for (int j = 0; j < 8; ++j) acc[qq][j] = 0.f;

  #pragma unroll
  for (int tile = 0; tile < 4; ++tile) {
    __syncthreads();
    for (int i = t; i < 128 * 16; i += 256) {
      const int row = i >> 4, e4 = i & 15;
      kp4[row][e4 ^ (row & 7)] =
          reinterpret_cast<const float4*>(kbase + (tile * 128 + row) * 64)[e4];
    }
    __syncthreads();
    #pragma unroll 4
    for (int e4 = 0; e4 < 16; ++e4) {
      const float4 qa = *reinterpret_cast<const float4*>(&qsh[tqg * 2 + 0][e4 * 4]);
      const float4 qb = *reinterpret_cast<const float4*>(&qsh[tqg * 2 + 1][e4 * 4]);
      const float4 w4 = *reinterpret_cast<const float4*>(&w2s[e4 * 4]);
      #pragma unroll
      for (int jj = 0; jj < 2; ++jj) {
        const int kk = jj * 64 + tk;
        const float4 kv = kp4[kk][e4 ^ (kk & 7)];
        const int j = tile * 2 + jj;
        float a0 = acc[0][j], a1 = acc[1][j];
        a0 = fmaf(w4.x, sig2(qa.x + kv.x), a0);
        a0 = fmaf(w4.y, sig2(qa.y + kv.y), a0);
        a0 = fmaf(w4.z, sig2(qa.z + kv.z), a0);
        a0 = fmaf(w4.w, sig2(qa.w + kv.w), a0);
        a1 = fmaf(w4.x, sig2(qb.x + kv.x), a1);
        a1 = fmaf(w4.y, sig2(qb.y + kv.y), a1);
        a1 = fmaf(w4.z, sig2(qb.z + kv.z), a1);
        a1 = fmaf(w4.w, sig2(qb.w + kv.w), a1);
        acc[0][j] = a0; acc[1][j] = a1;
      }
    }
  }

  // ---- mask + softmax (rows live on one wave each: full-wave shfl) ----
  const int* __restrict__ mrow0 = mask + (b * 512 + q0 + 0) * 512;
  const int* __restrict__ mrow1 = mask + (b * 512 + q0 + 1) * 512;
  int mv0[8], mv1[8];
  #pragma unroll
  for (int j = 0; j < 8; ++j) {
    const int k = (j >> 1) * 128 + (j & 1) * 64 + tk;
    mv0[j] = mrow0[k];
    mv1[j] = mrow1[k];
  }
  int lo0 = 0, lo1 = 0;
  #pragma unroll
  for (int j = 0; j < 8; ++j) { lo0 |= mv0[j]; lo1 |= mv1[j]; }
  const bool rowany0 = __any(lo0 != 0);
  const bool rowany1 = __any(lo1 != 0);
  const float NEG = -__builtin_inff();
  #pragma unroll
  for (int j = 0; j < 8; ++j) {
    if (rowany0 && mv0[j] == 0) acc[0][j] = NEG;
    if (rowany1 && mv1[j] == 0) acc[1][j] = NEG;
  }

  float m0 = acc[0][0], m1 = acc[1][0];
  #pragma unroll
  for (int j = 1; j < 8; ++j) { m0 = fmaxf(m0, acc[0][j]); m1 = fmaxf(m1, acc[1][j]); }
  #pragma unroll
  for (int s = 1; s < 64; s <<= 1) {
    m0 = fmaxf(m0, __shfl_xor(m0, s));
    m1 = fmaxf(m1, __shfl_xor(m1, s));
  }

  const float L2E = 1.4426950408889634f;
  const float c0 = m0 * L2E, c1 = m1 * L2E;
  float p0[8], p1[8];
  float s0 = 0.f, s1 = 0.f;
  #pragma unroll
  for (int j = 0; j < 8; ++j) {
    p0[j] = __builtin_amdgcn_exp2f(fmaf(acc[0][j], L2E, -c0));
    p1[j] = __builtin_amdgcn_exp2f(fmaf(acc[1][j], L2E, -c1));
    s0 += p0[j]; s1 += p1[j];
  }
  #pragma unroll
  for (int s = 1; s < 64; s <<= 1) {
    s0 += __shfl_xor(s0, s);
    s1 += __shfl_xor(s1, s);
  }
  const float inv0 = 1.0f / s0, inv1 = 1.0f / s1;

  float* __restrict__ o0 = out + (bh * 512 + q0 + 0) * 512;
  float* __restrict__ o1 = out + (bh * 512 + q0 + 1) * 512;
  #pragma unroll
  for (int j = 0; j < 8; ++j) {
    const int k = (j >> 1) * 128 + (j & 1) * 64 + tk;
    o0[k] = p0[j] * inv0;
    o1[k] = p1[j] * inv1;
  }
}

extern "C" void kernel_launch(void* const* d_in, const int* in_sizes, int n_in,
                              void* d_out, int out_size, void* d_ws, size_t ws_size,
                              hipStream_t stream) {
  const float* Q  = (const float*)d_in[0];
  const float* K  = (const float*)d_in[1];
  // d_in[2] = values : unused by the reference output
  const int*   M  = (const int*)d_in[3];
  const float* W  = (const float*)d_in[4];
  const float* bC = (const float*)d_in[5];
  const float* wl = (const float*)d_in[6];
  // d_in[7] = b_logit : uniform shift, cancels in softmax
  float* out = (float*)d_out;
  float* qs = (float*)d_ws;            // 4096*64 floats = 1MB
  float* ks = qs + NQROWS * 64;        // 1MB

  proj_kernel<<<512, 256, 0, stream>>>(Q, K, W, bC, qs, ks);
  attn_kernel<<<512, 256, 0, stream>>>(qs, ks, wl, M, out);
}